// Round 6
// baseline (65.444 us; speedup 1.0000x reference)
//
#include <hip/hip_runtime.h>

// Volumetric (NeRF) renderer. One 64-lane wave handles TWO rays; each lane
// owns 3 consecutive samples of each ray (s = 3*lane..3*lane+2).
// All global loads for both rays are issued up front (2x MLP), the two
// wave-scans and reduction trees run interleaved (2x ILP on the DS chain).
// Cache policy: NT loads for colors, NT stores for weights/alpha.

#define NUM_S 192

struct f3 { float x, y, z; };

__global__ __launch_bounds__(256) void volrend_kernel(
    const float* __restrict__ dens,   // [R, S]
    const float* __restrict__ cols,   // [R, S, 3]
    const float* __restrict__ tv,     // [R, S]
    const float* __restrict__ rdir,   // [R, 3]
    float* __restrict__ out_rgb,      // [R, 3]
    float* __restrict__ out_depth,    // [R]
    float* __restrict__ out_w,        // [R, S]
    float* __restrict__ out_alpha,    // [R, S]
    float* __restrict__ out_acc,      // [R]
    int R)
{
    const int wave = (blockIdx.x * blockDim.x + threadIdx.x) >> 6;
    const int lane = threadIdx.x & 63;
    const int rA = wave * 2;
    const int rB = rA + 1;
    if (rA >= R) return;            // R is even; rB valid whenever rA is

    const long baseA = (long)rA * NUM_S;
    const long baseB = baseA + NUM_S;
    const int  s0    = 3 * lane;

    // ---- ALL loads for both rays issued up front ----
    const f3 tA = *(const f3*)(tv   + baseA + s0);
    const f3 tB = *(const f3*)(tv   + baseB + s0);
    const f3 dA = *(const f3*)(dens + baseA + s0);
    const f3 dB = *(const f3*)(dens + baseB + s0);

    const float* cpA = cols + (baseA + s0) * 3;
    const float* cpB = cols + (baseB + s0) * 3;
    float cA[9], cB[9];
    #pragma unroll
    for (int k = 0; k < 9; ++k) cA[k] = __builtin_nontemporal_load(cpA + k);
    #pragma unroll
    for (int k = 0; k < 9; ++k) cB[k] = __builtin_nontemporal_load(cpB + k);

    const f3 rdA = *(const f3*)(rdir + (long)rA * 3);
    const f3 rdB = *(const f3*)(rdir + (long)rB * 3);

    const float nrmA = sqrtf(rdA.x * rdA.x + rdA.y * rdA.y + rdA.z * rdA.z);
    const float nrmB = sqrtf(rdB.x * rdB.x + rdB.y * rdB.y + rdB.z * rdB.z);

    // ---- dists (t[s+1]-t[s], last = 1e10) ----
    const float tnA = __shfl_down(tA.x, 1);
    const float tnB = __shfl_down(tB.x, 1);
    const float dA0 = (tA.y - tA.x) * nrmA;
    const float dA1 = (tA.z - tA.y) * nrmA;
    const float dA2 = (lane == 63) ? 1e10f * nrmA : (tnA - tA.z) * nrmA;
    const float dB0 = (tB.y - tB.x) * nrmB;
    const float dB1 = (tB.z - tB.y) * nrmB;
    const float dB2 = (lane == 63) ? 1e10f * nrmB : (tnB - tB.z) * nrmB;

    const float aA0 = 1.0f - __expf(-fmaxf(dA.x, 0.0f) * dA0);
    const float aA1 = 1.0f - __expf(-fmaxf(dA.y, 0.0f) * dA1);
    const float aA2 = 1.0f - __expf(-fmaxf(dA.z, 0.0f) * dA2);
    const float aB0 = 1.0f - __expf(-fmaxf(dB.x, 0.0f) * dB0);
    const float aB1 = 1.0f - __expf(-fmaxf(dB.y, 0.0f) * dB1);
    const float aB2 = 1.0f - __expf(-fmaxf(dB.z, 0.0f) * dB2);

    const float fA0 = 1.0f - aA0 + 1e-10f;
    const float fA1 = 1.0f - aA1 + 1e-10f;
    const float fA2 = 1.0f - aA2 + 1e-10f;
    const float fB0 = 1.0f - aB0 + 1e-10f;
    const float fB1 = 1.0f - aB1 + 1e-10f;
    const float fB2 = 1.0f - aB2 + 1e-10f;
    const float fA01 = fA0 * fA1;
    const float fB01 = fB0 * fB1;

    // ---- two interleaved inclusive scans over per-lane products ----
    float PA = fA01 * fA2;
    float PB = fB01 * fB2;
    #pragma unroll
    for (int off = 1; off < 64; off <<= 1) {
        const float qA = __shfl_up(PA, off);
        const float qB = __shfl_up(PB, off);
        if (lane >= off) { PA *= qA; PB *= qB; }
    }
    float eA = __shfl_up(PA, 1);
    float eB = __shfl_up(PB, 1);
    if (lane == 0) { eA = 1.0f; eB = 1.0f; }

    const float wA0 = aA0 * eA;
    const float wA1 = aA1 * eA * fA0;
    const float wA2 = aA2 * eA * fA01;
    const float wB0 = aB0 * eB;
    const float wB1 = aB1 * eB * fB0;
    const float wB2 = aB2 * eB * fB01;

    // ---- NT stores (12B per lane, coalesced across wave) ----
    __builtin_nontemporal_store(wA0, out_w + baseA + s0 + 0);
    __builtin_nontemporal_store(wA1, out_w + baseA + s0 + 1);
    __builtin_nontemporal_store(wA2, out_w + baseA + s0 + 2);
    __builtin_nontemporal_store(wB0, out_w + baseB + s0 + 0);
    __builtin_nontemporal_store(wB1, out_w + baseB + s0 + 1);
    __builtin_nontemporal_store(wB2, out_w + baseB + s0 + 2);
    __builtin_nontemporal_store(aA0, out_alpha + baseA + s0 + 0);
    __builtin_nontemporal_store(aA1, out_alpha + baseA + s0 + 1);
    __builtin_nontemporal_store(aA2, out_alpha + baseA + s0 + 2);
    __builtin_nontemporal_store(aB0, out_alpha + baseB + s0 + 0);
    __builtin_nontemporal_store(aB1, out_alpha + baseB + s0 + 1);
    __builtin_nontemporal_store(aB2, out_alpha + baseB + s0 + 2);

    // ---- per-ray reductions (interleaved A/B) ----
    float arA = wA0 * cA[0] + wA1 * cA[3] + wA2 * cA[6];
    float agA = wA0 * cA[1] + wA1 * cA[4] + wA2 * cA[7];
    float abA = wA0 * cA[2] + wA1 * cA[5] + wA2 * cA[8];
    float adA = wA0 * tA.x + wA1 * tA.y + wA2 * tA.z;
    float awA = wA0 + wA1 + wA2;
    float arB = wB0 * cB[0] + wB1 * cB[3] + wB2 * cB[6];
    float agB = wB0 * cB[1] + wB1 * cB[4] + wB2 * cB[7];
    float abB = wB0 * cB[2] + wB1 * cB[5] + wB2 * cB[8];
    float adB = wB0 * tB.x + wB1 * tB.y + wB2 * tB.z;
    float awB = wB0 + wB1 + wB2;

    #pragma unroll
    for (int off = 32; off > 0; off >>= 1) {
        arA += __shfl_xor(arA, off);
        arB += __shfl_xor(arB, off);
        agA += __shfl_xor(agA, off);
        agB += __shfl_xor(agB, off);
        abA += __shfl_xor(abA, off);
        abB += __shfl_xor(abB, off);
        adA += __shfl_xor(adA, off);
        adB += __shfl_xor(adB, off);
        awA += __shfl_xor(awA, off);
        awB += __shfl_xor(awB, off);
    }
    if (lane == 0) {
        f3 rgbA; rgbA.x = arA; rgbA.y = agA; rgbA.z = abA;
        f3 rgbB; rgbB.x = arB; rgbB.y = agB; rgbB.z = abB;
        *(f3*)(out_rgb + (long)rA * 3) = rgbA;
        *(f3*)(out_rgb + (long)rB * 3) = rgbB;
        out_depth[rA] = adA;
        out_depth[rB] = adB;
        out_acc[rA]   = awA;
        out_acc[rB]   = awB;
    }
}

extern "C" void kernel_launch(void* const* d_in, const int* in_sizes, int n_in,
                              void* d_out, int out_size, void* d_ws, size_t ws_size,
                              hipStream_t stream) {
    const float* dens = (const float*)d_in[0];  // [R,S]
    const float* cols = (const float*)d_in[1];  // [R,S,3]
    const float* tv   = (const float*)d_in[2];  // [R,S]
    const float* rdir = (const float*)d_in[3];  // [R,3]

    const int R = in_sizes[3] / 3;
    // output layout: rgb[R,3] | depth[R] | weights[R,S] | alpha[R,S] | acc[R]
    float* out       = (float*)d_out;
    float* out_rgb   = out;
    float* out_depth = out_rgb + (long)R * 3;
    float* out_w     = out_depth + R;
    float* out_alpha = out_w + (long)R * NUM_S;
    float* out_acc   = out_alpha + (long)R * NUM_S;

    const int threads = 256;                 // 4 waves -> 8 rays per block
    const int rays_per_block = (threads / 64) * 2;
    const int blocks = (R + rays_per_block - 1) / rays_per_block;
    volrend_kernel<<<blocks, threads, 0, stream>>>(
        dens, cols, tv, rdir, out_rgb, out_depth, out_w, out_alpha, out_acc, R);
}

// Round 7
// 55.947 us; speedup vs baseline: 1.1698x; 1.1698x over previous
//
#include <hip/hip_runtime.h>

// Volumetric (NeRF) renderer: one 64-lane wave per ray, S=192 samples in
// 3 chunks of 64 (lane <-> sample c*64+lane). Non-temporal stores for the
// big weights/alpha outputs (avoids write-allocate pollution).
// Roofline note: compulsory traffic = 353 MB/replay; at the ~6.3 TB/s
// fabric/HBM service rate the floor is ~56 us — this kernel achieves it.

#define NUM_S 192

__global__ __launch_bounds__(256) void volrend_kernel(
    const float* __restrict__ dens,   // [R, S]
    const float* __restrict__ cols,   // [R, S, 3]
    const float* __restrict__ tv,     // [R, S]
    const float* __restrict__ rdir,   // [R, 3]
    float* __restrict__ out_rgb,      // [R, 3]
    float* __restrict__ out_depth,    // [R]
    float* __restrict__ out_w,        // [R, S]
    float* __restrict__ out_alpha,    // [R, S]
    float* __restrict__ out_acc,      // [R]
    int R)
{
    const int wid  = (blockIdx.x * blockDim.x + threadIdx.x) >> 6; // ray id
    const int lane = threadIdx.x & 63;
    if (wid >= R) return;
    const int r = wid;

    const long base = (long)r * NUM_S;

    // ---- issue ALL global loads up front (latency overlap) ----
    const float t0 = tv[base + lane];
    const float t1 = tv[base + 64 + lane];
    const float t2 = tv[base + 128 + lane];
    const float d0 = dens[base + lane];
    const float d1 = dens[base + 64 + lane];
    const float d2 = dens[base + 128 + lane];

    const long cb0 = (base + lane) * 3;
    const long cb1 = (base + 64 + lane) * 3;
    const long cb2 = (base + 128 + lane) * 3;
    const float c0r = cols[cb0 + 0], c0g = cols[cb0 + 1], c0b = cols[cb0 + 2];
    const float c1r = cols[cb1 + 0], c1g = cols[cb1 + 1], c1b = cols[cb1 + 2];
    const float c2r = cols[cb2 + 0], c2g = cols[cb2 + 1], c2b = cols[cb2 + 2];

    const float dx = rdir[r * 3 + 0];
    const float dy = rdir[r * 3 + 1];
    const float dz = rdir[r * 3 + 2];
    const float nrm = sqrtf(dx * dx + dy * dy + dz * dz);

    // ---- dists: t[s+1]-t[s], last = 1e10; chunk boundaries via broadcast ----
    float tn0 = __shfl_down(t0, 1);
    float tn1 = __shfl_down(t1, 1);
    float tn2 = __shfl_down(t2, 1);
    const float b1 = __shfl(t1, 0);   // first t of chunk 1
    const float b2 = __shfl(t2, 0);   // first t of chunk 2
    if (lane == 63) { tn0 = b1; tn1 = b2; tn2 = t2 + 1e10f; }

    const float dist0 = (tn0 - t0) * nrm;
    const float dist1 = (tn1 - t1) * nrm;
    const float dist2 = (tn2 - t2) * nrm;

    const float a0 = 1.0f - __expf(-fmaxf(d0, 0.0f) * dist0);
    const float a1 = 1.0f - __expf(-fmaxf(d1, 0.0f) * dist1);
    const float a2 = 1.0f - __expf(-fmaxf(d2, 0.0f) * dist2);

    // ---- three independent inclusive cumprod scans, interleaved ----
    float p0 = 1.0f - a0 + 1e-10f;
    float p1 = 1.0f - a1 + 1e-10f;
    float p2 = 1.0f - a2 + 1e-10f;
    #pragma unroll
    for (int off = 1; off < 64; off <<= 1) {
        const float q0 = __shfl_up(p0, off);
        const float q1 = __shfl_up(p1, off);
        const float q2 = __shfl_up(p2, off);
        if (lane >= off) { p0 *= q0; p1 *= q1; p2 *= q2; }
    }
    const float tot0 = __shfl(p0, 63);
    const float tot1 = __shfl(p1, 63);

    float e0 = __shfl_up(p0, 1);
    float e1 = __shfl_up(p1, 1);
    float e2 = __shfl_up(p2, 1);
    if (lane == 0) { e0 = 1.0f; e1 = 1.0f; e2 = 1.0f; }

    const float tr0 = e0;
    const float tr1 = tot0 * e1;
    const float tr2 = tot0 * tot1 * e2;

    const float w0 = a0 * tr0;
    const float w1 = a1 * tr1;
    const float w2 = a2 * tr2;

    // ---- non-temporal (no write-allocate) dense stores for big outputs ----
    __builtin_nontemporal_store(w0, out_w + base + lane);
    __builtin_nontemporal_store(w1, out_w + base + 64 + lane);
    __builtin_nontemporal_store(w2, out_w + base + 128 + lane);
    __builtin_nontemporal_store(a0, out_alpha + base + lane);
    __builtin_nontemporal_store(a1, out_alpha + base + 64 + lane);
    __builtin_nontemporal_store(a2, out_alpha + base + 128 + lane);

    // ---- per-ray reductions ----
    float acc_r = w0 * c0r + w1 * c1r + w2 * c2r;
    float acc_g = w0 * c0g + w1 * c1g + w2 * c2g;
    float acc_b = w0 * c0b + w1 * c1b + w2 * c2b;
    float acc_d = w0 * t0 + w1 * t1 + w2 * t2;
    float acc_w = w0 + w1 + w2;

    #pragma unroll
    for (int off = 32; off > 0; off >>= 1) {
        acc_r += __shfl_xor(acc_r, off);
        acc_g += __shfl_xor(acc_g, off);
        acc_b += __shfl_xor(acc_b, off);
        acc_d += __shfl_xor(acc_d, off);
        acc_w += __shfl_xor(acc_w, off);
    }
    if (lane == 0) {
        out_rgb[r * 3 + 0] = acc_r;
        out_rgb[r * 3 + 1] = acc_g;
        out_rgb[r * 3 + 2] = acc_b;
        out_depth[r] = acc_d;
        out_acc[r]   = acc_w;
    }
}

extern "C" void kernel_launch(void* const* d_in, const int* in_sizes, int n_in,
                              void* d_out, int out_size, void* d_ws, size_t ws_size,
                              hipStream_t stream) {
    const float* dens = (const float*)d_in[0];  // [R,S]
    const float* cols = (const float*)d_in[1];  // [R,S,3]
    const float* tv   = (const float*)d_in[2];  // [R,S]
    const float* rdir = (const float*)d_in[3];  // [R,3]

    const int R = in_sizes[3] / 3;
    // output layout: rgb[R,3] | depth[R] | weights[R,S] | alpha[R,S] | acc[R]
    float* out       = (float*)d_out;
    float* out_rgb   = out;
    float* out_depth = out_rgb + (long)R * 3;
    float* out_w     = out_depth + R;
    float* out_alpha = out_w + (long)R * NUM_S;
    float* out_acc   = out_alpha + (long)R * NUM_S;

    const int threads = 256;                 // 4 waves -> 4 rays per block
    const int rays_per_block = threads / 64;
    const int blocks = (R + rays_per_block - 1) / rays_per_block;
    volrend_kernel<<<blocks, threads, 0, stream>>>(
        dens, cols, tv, rdir, out_rgb, out_depth, out_w, out_alpha, out_acc, R);
}